// Round 3
// baseline (391.724 us; speedup 1.0000x reference)
//
#include <hip/hip_runtime.h>

#define T_SEQ   2048
#define DH      128
#define WINDOW  512
#define BM      128          // q rows per block = 4 waves x 32
#define BN      64           // keys per tile
#define NT      32           // tiles per bh
#define TILE_US 16384        // ushorts per (K,Vt) tile pair (32 KB)
#define SCALE_LOG2E 0.12751744250f   // (1/sqrt(128)) * log2(e)  -> use exp2

typedef unsigned short ushort_t;
typedef __attribute__((ext_vector_type(8))) unsigned short ushort8;
typedef __attribute__((ext_vector_type(4))) unsigned short ushort4v;
typedef __attribute__((ext_vector_type(4))) float float4v;
typedef __attribute__((ext_vector_type(16))) float float16v;
typedef __attribute__((ext_vector_type(8))) __bf16 bf16x8;

union U8 { ushort8 us; bf16x8 bf; unsigned u[4]; };
union FU { float f; unsigned u; };

__device__ __forceinline__ unsigned short f2bf(float f) {
  FU x; x.f = f;
  unsigned r = x.u + 0x7FFFu + ((x.u >> 16) & 1u);   // RNE
  return (unsigned short)(r >> 16);
}

// ---------------------------------------------------------------------------
// pack_kv: fp32 K,V -> bf16 tile images in ws, via LDS bounce (all global
// writes coalesced). Per tile (32 KB): [0..8191] K[key][d] with 16B-block
// swizzle c8^=(key&7); [8192..16383] Vt[d][pos] where pos = key with bits
// 2,3 swapped (sigma order for lane-local P fragments) and block swizzle
// B^=(d&7).
// ---------------------------------------------------------------------------
__global__ __launch_bounds__(256)
void pack_kv(const float* __restrict__ kg, const float* __restrict__ vg,
             ushort_t* __restrict__ ws)
{
  __shared__ __align__(16) ushort_t sb[TILE_US];
  const int tile = blockIdx.x;
  const int tid  = threadIdx.x;
  const size_t src = (size_t)tile * (BN * DH);
  const float* kb = kg + src;
  const float* vb = vg + src;

  // K phase: coalesced reads, swizzled LDS writes (conflict-free pattern)
#pragma unroll
  for (int rep = 0; rep < 4; ++rep) {
    const int b   = rep * 256 + tid;
    const int key = b >> 4;
    const int c8  = b & 15;
    const float* s = kb + key * DH + c8 * 8;
    float4v a = *(const float4v*)s;
    float4v c = *(const float4v*)(s + 4);
    U8 h;
    h.us[0]=f2bf(a[0]); h.us[1]=f2bf(a[1]); h.us[2]=f2bf(a[2]); h.us[3]=f2bf(a[3]);
    h.us[4]=f2bf(c[0]); h.us[5]=f2bf(c[1]); h.us[6]=f2bf(c[2]); h.us[7]=f2bf(c[3]);
    *(ushort8*)(sb + key * DH + ((c8 ^ (key & 7)) << 3)) = h.us;
  }

  // V phase: register 4x4 transpose, write into sigma+swizzle layout in LDS
  {
    const int cb  = tid >> 3;     // d block 0..31
    const int rb0 = tid & 7;
#pragma unroll
    for (int it = 0; it < 2; ++it) {
      const int rb = rb0 + it * 8;           // keys rb*4 .. rb*4+3
      const float* s = vb + (size_t)(rb * 4) * DH + cb * 4;
      float4v r0 = *(const float4v*)(s);
      float4v r1 = *(const float4v*)(s + DH);
      float4v r2 = *(const float4v*)(s + 2 * DH);
      float4v r3 = *(const float4v*)(s + 3 * DH);
      const int B    = (rb & 1) | ((rb >> 2) << 1);   // 16B-block index 0..7
      const int off4 = ((rb >> 1) & 1) << 2;          // half-block offset
#pragma unroll
      for (int c = 0; c < 4; ++c) {
        const int d = cb * 4 + c;
        ushort4v h;
        h[0]=f2bf(r0[c]); h[1]=f2bf(r1[c]); h[2]=f2bf(r2[c]); h[3]=f2bf(r3[c]);
        *(ushort4v*)(sb + 8192 + d * BN + ((B ^ (d & 7)) << 3) + off4) = h;
      }
    }
  }
  __syncthreads();

  // copy out: fully coalesced 16B/lane linear
  ushort_t* wt = ws + (size_t)tile * TILE_US;
#pragma unroll
  for (int rep = 0; rep < 8; ++rep) {
    const int off = (rep * 256 + tid) * 8;
    *(ushort8*)(wt + off) = *(const ushort8*)(sb + off);
  }
}

// ---------------------------------------------------------------------------
// swa_fwd: flash attention, S^T formulation with 32x32x16 MFMA.
//   S^T = K Q^T  (A=K frag, B=Q frag)  -> C-layout: col=q, row=key
//   O^T = V^T P^T (A=Vt frag, B=P frag) -> P B-frag is LANE-LOCAL thanks to
//   the sigma key order baked into Vt storage. No P LDS buffer, no shuffles.
//
// Staging (round 3, T14 reg-staged async-split): each 32 KB tile flows
// global -> 32 VGPRs/lane -> LDS. Loads for tile t+1 are issued right after
// the barrier at the top of iteration t, and their (register-precise,
// compiler-inserted) waits land at the end-of-iteration __syncthreads /
// next iteration's ds_write — i.e. the HBM/L3 latency is hidden under the
// full S+softmax+PV compute phase instead of being exposed at the top of
// every iteration (the round-0 baseline drained vmcnt(0) against a
// freshly-issued global_load_lds tile each iteration).
// NOTE: global_load_lds was abandoned (rounds 1-2): with runtime slot bases
// the compiler cannot prove DMA/ds_read disjointness and inserts vmcnt(0)
// before the first LDS read, draining the prefetch mid-compute.
// Barrier structure, math, and layouts are identical to round 0.
// ---------------------------------------------------------------------------
__global__ __launch_bounds__(256, 3)
void swa_fwd(const float* __restrict__ qg, const ushort_t* __restrict__ ws,
             float* __restrict__ og)
{
  __shared__ __align__(16) ushort_t lds[TILE_US];   // 32 KB: K | Vt

  const int qt   = (gridDim.x - 1) - blockIdx.x;    // heavy blocks first
  const int bh   = blockIdx.y;
  const int tid  = threadIdx.x;
  const int wv   = tid >> 6;
  const int lane = tid & 63;
  const int l32  = lane & 31;
  const int half = lane >> 5;
  const int l7   = l32 & 7;

  const size_t base = (size_t)bh * (T_SEQ * DH);
  const float* qb = qg + base;
  float*       ob = og + base;
  const ushort_t* wsb = ws + (size_t)bh * NT * TILE_US;

  const int i0w = qt * BM + wv * 32;   // wave's first q row (M=32 per wave)
  const int iq  = i0w + l32;           // this lane's q row

  const int lo  = qt * BM - (WINDOW - 1);
  const int kt0 = (lo > 0) ? (lo >> 6) : 0;
  const int kt1 = 2 * qt + 1;

  // ---- prologue: issue tile kt0's global loads into regs first ----
  ushort8 st[8];
  {
    const ushort_t* wt = wsb + (size_t)kt0 * TILE_US;
#pragma unroll
    for (int i = 0; i < 8; ++i)
      st[i] = *(const ushort8*)(wt + (i * 256 + tid) * 8);
  }

  // Q B-frags: B[k=d][n=q], lane n=l32, k = ks*16 + half*8 + j. Scale*log2e
  // folded. These loads overlap the tile-kt0 loads above.
  bf16x8 qf[8];
  {
    const float* qrow = qb + (size_t)iq * DH + half * 8;
#pragma unroll
    for (int ks = 0; ks < 8; ++ks) {
      float4v a = *(const float4v*)(qrow + ks * 16);
      float4v b = *(const float4v*)(qrow + ks * 16 + 4);
      U8 u;
      u.us[0]=f2bf(a[0]*SCALE_LOG2E); u.us[1]=f2bf(a[1]*SCALE_LOG2E);
      u.us[2]=f2bf(a[2]*SCALE_LOG2E); u.us[3]=f2bf(a[3]*SCALE_LOG2E);
      u.us[4]=f2bf(b[0]*SCALE_LOG2E); u.us[5]=f2bf(b[1]*SCALE_LOG2E);
      u.us[6]=f2bf(b[2]*SCALE_LOG2E); u.us[7]=f2bf(b[3]*SCALE_LOG2E);
      qf[ks] = u.bf;
    }
  }

  float16v O[4];
#pragma unroll
  for (int dc = 0; dc < 4; ++dc) O[dc] = (float16v)(0.0f);
  float m = -1e30f, l = 0.f;

  for (int kt = kt0; kt <= kt1; ++kt) {
    // ---- stage: regs -> LDS (data arrived long ago; waits are precise) ----
#pragma unroll
    for (int i = 0; i < 8; ++i)
      *(ushort8*)(lds + (i * 256 + tid) * 8) = st[i];
    __syncthreads();

    // ---- prefetch tile kt+1 into regs; consumed only next iteration ----
    if (kt < kt1) {
      const ushort_t* wt = wsb + (size_t)(kt + 1) * TILE_US;
#pragma unroll
      for (int i = 0; i < 8; ++i)
        st[i] = *(const ushort8*)(wt + (i * 256 + tid) * 8);
    }

    const int j0 = kt * BN;
    const bool active = (j0 <= i0w + 31) && (i0w - j0 - 63 < WINDOW);
    if (active) {
      // ---- S^T: 2 key-chunks x 8 k-steps of 32x32x16 ----
      float16v sv[2];
#pragma unroll
      for (int c = 0; c < 2; ++c) {
        float16v acc = (float16v)(0.0f);
        const ushort_t* krow = lds + (c * 32 + l32) * DH;
#pragma unroll
        for (int ks = 0; ks < 8; ++ks) {
          U8 a; a.us = *(const ushort8*)(krow + (((2 * ks + half) ^ l7) << 3));
          acc = __builtin_amdgcn_mfma_f32_32x32x16_bf16(a.bf, qf[ks], acc, 0, 0, 0);
        }
        sv[c] = acc;
      }

      // ---- mask (edge tiles only). row(key)=(reg&3)+8*(reg>>2)+4*half ----
      const bool full = (j0 + 63 <= i0w) && ((i0w + 31) - j0 < WINDOW);
      if (!full) {
#pragma unroll
        for (int c = 0; c < 2; ++c) {
#pragma unroll
          for (int r = 0; r < 16; ++r) {
            const int j = j0 + c * 32 + (r & 3) + 8 * (r >> 2) + 4 * half;
            const bool ok = (j <= iq) && ((iq - j) < WINDOW);
            sv[c][r] = ok ? sv[c][r] : -1e30f;
          }
        }
      }

      // ---- online softmax (log2 domain; one q row per lane) ----
      float mt = sv[0][0];
#pragma unroll
      for (int r = 1; r < 16; ++r) mt = fmaxf(mt, sv[0][r]);
#pragma unroll
      for (int r = 0; r < 16; ++r) mt = fmaxf(mt, sv[1][r]);
      mt = fmaxf(mt, __shfl_xor(mt, 32));
      const float mn = fmaxf(m, mt);
      const float alpha = __builtin_amdgcn_exp2f(m - mn);
      m = mn;

      float ps = 0.f;
      unsigned pk[2][8];
#pragma unroll
      for (int c = 0; c < 2; ++c) {
#pragma unroll
        for (int rg = 0; rg < 8; ++rg) {
          FU p0, p1;
          p0.f = __builtin_amdgcn_exp2f(sv[c][2 * rg]     - m);
          p1.f = __builtin_amdgcn_exp2f(sv[c][2 * rg + 1] - m);
          p0.u &= 0xFFFF0000u; p1.u &= 0xFFFF0000u;   // truncate to bf16
          ps += p0.f + p1.f;                           // l matches P exactly
          pk[c][rg] = (p0.u >> 16) | p1.u;
        }
      }
      l = l * alpha + ps;
#pragma unroll
      for (int dc = 0; dc < 4; ++dc)
#pragma unroll
        for (int r = 0; r < 16; ++r) O[dc][r] *= alpha;

      // ---- O^T += V^T P^T : B-frag for k-step s = sv regs [8(s&1)..+7] ----
#pragma unroll
      for (int s = 0; s < 4; ++s) {
        const int c = s >> 1, o = (s & 1) * 4;
        U8 b;
        b.u[0] = pk[c][o]; b.u[1] = pk[c][o + 1];
        b.u[2] = pk[c][o + 2]; b.u[3] = pk[c][o + 3];
        const int blk = ((2 * s + half) ^ l7) << 3;
#pragma unroll
        for (int dc = 0; dc < 4; ++dc) {
          U8 a; a.us = *(const ushort8*)(lds + 8192 + (dc * 32 + l32) * BN + blk);
          O[dc] = __builtin_amdgcn_mfma_f32_32x32x16_bf16(a.bf, b.bf, O[dc], 0, 0, 0);
        }
      }
    }
    __syncthreads();
  }

  // ---- epilogue: fold halves of l, normalize, store ----
  l += __shfl_xor(l, 32);
  const float linv = 1.0f / l;
  float* orow = ob + (size_t)iq * DH;
#pragma unroll
  for (int dc = 0; dc < 4; ++dc) {
#pragma unroll
    for (int g = 0; g < 4; ++g) {
      float4v o4;
      o4[0] = O[dc][g * 4 + 0] * linv; o4[1] = O[dc][g * 4 + 1] * linv;
      o4[2] = O[dc][g * 4 + 2] * linv; o4[3] = O[dc][g * 4 + 3] * linv;
      *(float4v*)(orow + dc * 32 + g * 8 + half * 4) = o4;
    }
  }
}

extern "C" void kernel_launch(void* const* d_in, const int* in_sizes, int n_in,
                              void* d_out, int out_size, void* d_ws, size_t ws_size,
                              hipStream_t stream) {
  const float* q = (const float*)d_in[0];
  const float* k = (const float*)d_in[1];
  const float* v = (const float*)d_in[2];
  float* o = (float*)d_out;
  const int bh_count = in_sizes[0] / (T_SEQ * DH);   // 64
  ushort_t* ws = (ushort_t*)d_ws;                    // 64 MB used

  pack_kv<<<dim3(bh_count * NT), 256, 0, stream>>>(k, v, ws);
  swa_fwd<<<dim3(T_SEQ / BM, bh_count), 256, 0, stream>>>(q, ws, o);
}

// Round 4
// 275.693 us; speedup vs baseline: 1.4209x; 1.4209x over previous
//
#include <hip/hip_runtime.h>

#define T_SEQ   2048
#define DH      128
#define WINDOW  512
#define BM      128          // q rows per block = 4 waves x 32
#define BN      64           // keys per tile
#define NT      32           // tiles per bh
#define TILE_US 16384        // ushorts per (K,Vt) tile pair (32 KB)
#define SCALE_LOG2E 0.12751744250f   // (1/sqrt(128)) * log2(e)  -> use exp2

typedef unsigned short ushort_t;
typedef __attribute__((ext_vector_type(8))) unsigned short ushort8;
typedef __attribute__((ext_vector_type(4))) unsigned short ushort4v;
typedef __attribute__((ext_vector_type(4))) float float4v;
typedef __attribute__((ext_vector_type(16))) float float16v;
typedef __attribute__((ext_vector_type(8))) __bf16 bf16x8;

union U8 { ushort8 us; bf16x8 bf; unsigned u[4]; };
union FU { float f; unsigned u; };

__device__ __forceinline__ unsigned short f2bf(float f) {
  FU x; x.f = f;
  unsigned r = x.u + 0x7FFFu + ((x.u >> 16) & 1u);   // RNE
  return (unsigned short)(r >> 16);
}

// ---------------------------------------------------------------------------
// pack_kv: fp32 K,V -> bf16 tile images in ws, via LDS bounce (all global
// writes coalesced). Per tile (32 KB): [0..8191] K[key][d] with 16B-block
// swizzle c8^=(key&7); [8192..16383] Vt[d][pos] where pos = key with bits
// 2,3 swapped (sigma order for lane-local P fragments) and block swizzle
// B^=(d&7).
// ---------------------------------------------------------------------------
__global__ __launch_bounds__(256)
void pack_kv(const float* __restrict__ kg, const float* __restrict__ vg,
             ushort_t* __restrict__ ws)
{
  __shared__ __align__(16) ushort_t sb[TILE_US];
  const int tile = blockIdx.x;
  const int tid  = threadIdx.x;
  const size_t src = (size_t)tile * (BN * DH);
  const float* kb = kg + src;
  const float* vb = vg + src;

  // K phase: coalesced reads, swizzled LDS writes (conflict-free pattern)
#pragma unroll
  for (int rep = 0; rep < 4; ++rep) {
    const int b   = rep * 256 + tid;
    const int key = b >> 4;
    const int c8  = b & 15;
    const float* s = kb + key * DH + c8 * 8;
    float4v a = *(const float4v*)s;
    float4v c = *(const float4v*)(s + 4);
    U8 h;
    h.us[0]=f2bf(a[0]); h.us[1]=f2bf(a[1]); h.us[2]=f2bf(a[2]); h.us[3]=f2bf(a[3]);
    h.us[4]=f2bf(c[0]); h.us[5]=f2bf(c[1]); h.us[6]=f2bf(c[2]); h.us[7]=f2bf(c[3]);
    *(ushort8*)(sb + key * DH + ((c8 ^ (key & 7)) << 3)) = h.us;
  }

  // V phase: register 4x4 transpose, write into sigma+swizzle layout in LDS
  {
    const int cb  = tid >> 3;     // d block 0..31
    const int rb0 = tid & 7;
#pragma unroll
    for (int it = 0; it < 2; ++it) {
      const int rb = rb0 + it * 8;           // keys rb*4 .. rb*4+3
      const float* s = vb + (size_t)(rb * 4) * DH + cb * 4;
      float4v r0 = *(const float4v*)(s);
      float4v r1 = *(const float4v*)(s + DH);
      float4v r2 = *(const float4v*)(s + 2 * DH);
      float4v r3 = *(const float4v*)(s + 3 * DH);
      const int B    = (rb & 1) | ((rb >> 2) << 1);   // 16B-block index 0..7
      const int off4 = ((rb >> 1) & 1) << 2;          // half-block offset
#pragma unroll
      for (int c = 0; c < 4; ++c) {
        const int d = cb * 4 + c;
        ushort4v h;
        h[0]=f2bf(r0[c]); h[1]=f2bf(r1[c]); h[2]=f2bf(r2[c]); h[3]=f2bf(r3[c]);
        *(ushort4v*)(sb + 8192 + d * BN + ((B ^ (d & 7)) << 3) + off4) = h;
      }
    }
  }
  __syncthreads();

  // copy out: fully coalesced 16B/lane linear
  ushort_t* wt = ws + (size_t)tile * TILE_US;
#pragma unroll
  for (int rep = 0; rep < 8; ++rep) {
    const int off = (rep * 256 + tid) * 8;
    *(ushort8*)(wt + off) = *(const ushort8*)(sb + off);
  }
}

// ---------------------------------------------------------------------------
// swa_fwd: flash attention, S^T formulation with 32x32x16 MFMA.
//   S^T = K Q^T  (A=K frag, B=Q frag)  -> C-layout: col=q, row=key
//   O^T = V^T P^T (A=Vt frag, B=P frag) -> P B-frag is LANE-LOCAL thanks to
//   the sigma key order baked into Vt storage. No P LDS buffer, no shuffles.
//
// Staging (round 4 = round 3 + spill fix): each 32 KB tile flows
// global -> 32 VGPRs/lane -> LDS. Loads for tile t+1 are issued right after
// the barrier at the top of iteration t; the only waits on them (the
// end-of-iteration __syncthreads' vmcnt(0) drain / next iteration's
// ds_write) come a full compute phase (~1200+ cyc) after issue, so the
// ~600-cyc L3 latency is fully hidden. Register-precise waits — no LDS-DMA
// alias conservatism (the rounds-1/2 failure mode).
// ROUND-3 POST-MORTEM: __launch_bounds__(256, 3) capped VGPRs at ~170;
// peak pressure (O 64 + qf 32 + st 32 + pk 16 + addr) sat at the cap and
// the allocator spilled st[] to scratch (VGPR stayed 84, FETCH +160 MB,
// WRITE +143 MB, 204 us). Fix: min-waves 2 -> cap 256, st stays in VGPRs.
// ---------------------------------------------------------------------------
__global__ __launch_bounds__(256, 2)
void swa_fwd(const float* __restrict__ qg, const ushort_t* __restrict__ ws,
             float* __restrict__ og)
{
  __shared__ __align__(16) ushort_t lds[TILE_US];   // 32 KB: K | Vt

  const int qt   = (gridDim.x - 1) - blockIdx.x;    // heavy blocks first
  const int bh   = blockIdx.y;
  const int tid  = threadIdx.x;
  const int wv   = tid >> 6;
  const int lane = tid & 63;
  const int l32  = lane & 31;
  const int half = lane >> 5;
  const int l7   = l32 & 7;

  const size_t base = (size_t)bh * (T_SEQ * DH);
  const float* qb = qg + base;
  float*       ob = og + base;
  const ushort_t* wsb = ws + (size_t)bh * NT * TILE_US;

  const int i0w = qt * BM + wv * 32;   // wave's first q row (M=32 per wave)
  const int iq  = i0w + l32;           // this lane's q row

  const int lo  = qt * BM - (WINDOW - 1);
  const int kt0 = (lo > 0) ? (lo >> 6) : 0;
  const int kt1 = 2 * qt + 1;

  // ---- prologue: issue tile kt0's global loads into regs first ----
  ushort8 st[8];
  {
    const ushort_t* wt = wsb + (size_t)kt0 * TILE_US;
#pragma unroll
    for (int i = 0; i < 8; ++i)
      st[i] = *(const ushort8*)(wt + (i * 256 + tid) * 8);
  }

  // Q B-frags: B[k=d][n=q], lane n=l32, k = ks*16 + half*8 + j. Scale*log2e
  // folded. These loads overlap the tile-kt0 loads above.
  bf16x8 qf[8];
  {
    const float* qrow = qb + (size_t)iq * DH + half * 8;
#pragma unroll
    for (int ks = 0; ks < 8; ++ks) {
      float4v a = *(const float4v*)(qrow + ks * 16);
      float4v b = *(const float4v*)(qrow + ks * 16 + 4);
      U8 u;
      u.us[0]=f2bf(a[0]*SCALE_LOG2E); u.us[1]=f2bf(a[1]*SCALE_LOG2E);
      u.us[2]=f2bf(a[2]*SCALE_LOG2E); u.us[3]=f2bf(a[3]*SCALE_LOG2E);
      u.us[4]=f2bf(b[0]*SCALE_LOG2E); u.us[5]=f2bf(b[1]*SCALE_LOG2E);
      u.us[6]=f2bf(b[2]*SCALE_LOG2E); u.us[7]=f2bf(b[3]*SCALE_LOG2E);
      qf[ks] = u.bf;
    }
  }

  float16v O[4];
#pragma unroll
  for (int dc = 0; dc < 4; ++dc) O[dc] = (float16v)(0.0f);
  float m = -1e30f, l = 0.f;

  for (int kt = kt0; kt <= kt1; ++kt) {
    // ---- stage: regs -> LDS (data arrived long ago; waits are precise) ----
#pragma unroll
    for (int i = 0; i < 8; ++i)
      *(ushort8*)(lds + (i * 256 + tid) * 8) = st[i];
    __syncthreads();

    // ---- prefetch tile kt+1 into regs; consumed only next iteration ----
    if (kt < kt1) {
      const ushort_t* wt = wsb + (size_t)(kt + 1) * TILE_US;
#pragma unroll
      for (int i = 0; i < 8; ++i)
        st[i] = *(const ushort8*)(wt + (i * 256 + tid) * 8);
    }

    const int j0 = kt * BN;
    const bool active = (j0 <= i0w + 31) && (i0w - j0 - 63 < WINDOW);
    if (active) {
      // ---- S^T: 2 key-chunks x 8 k-steps of 32x32x16 ----
      float16v sv[2];
#pragma unroll
      for (int c = 0; c < 2; ++c) {
        float16v acc = (float16v)(0.0f);
        const ushort_t* krow = lds + (c * 32 + l32) * DH;
#pragma unroll
        for (int ks = 0; ks < 8; ++ks) {
          U8 a; a.us = *(const ushort8*)(krow + (((2 * ks + half) ^ l7) << 3));
          acc = __builtin_amdgcn_mfma_f32_32x32x16_bf16(a.bf, qf[ks], acc, 0, 0, 0);
        }
        sv[c] = acc;
      }

      // ---- mask (edge tiles only). row(key)=(reg&3)+8*(reg>>2)+4*half ----
      const bool full = (j0 + 63 <= i0w) && ((i0w + 31) - j0 < WINDOW);
      if (!full) {
#pragma unroll
        for (int c = 0; c < 2; ++c) {
#pragma unroll
          for (int r = 0; r < 16; ++r) {
            const int j = j0 + c * 32 + (r & 3) + 8 * (r >> 2) + 4 * half;
            const bool ok = (j <= iq) && ((iq - j) < WINDOW);
            sv[c][r] = ok ? sv[c][r] : -1e30f;
          }
        }
      }

      // ---- online softmax (log2 domain; one q row per lane) ----
      float mt = sv[0][0];
#pragma unroll
      for (int r = 1; r < 16; ++r) mt = fmaxf(mt, sv[0][r]);
#pragma unroll
      for (int r = 0; r < 16; ++r) mt = fmaxf(mt, sv[1][r]);
      mt = fmaxf(mt, __shfl_xor(mt, 32));
      const float mn = fmaxf(m, mt);
      const float alpha = __builtin_amdgcn_exp2f(m - mn);
      m = mn;

      float ps = 0.f;
      unsigned pk[2][8];
#pragma unroll
      for (int c = 0; c < 2; ++c) {
#pragma unroll
        for (int rg = 0; rg < 8; ++rg) {
          FU p0, p1;
          p0.f = __builtin_amdgcn_exp2f(sv[c][2 * rg]     - m);
          p1.f = __builtin_amdgcn_exp2f(sv[c][2 * rg + 1] - m);
          p0.u &= 0xFFFF0000u; p1.u &= 0xFFFF0000u;   // truncate to bf16
          ps += p0.f + p1.f;                           // l matches P exactly
          pk[c][rg] = (p0.u >> 16) | p1.u;
        }
      }
      l = l * alpha + ps;
#pragma unroll
      for (int dc = 0; dc < 4; ++dc)
#pragma unroll
        for (int r = 0; r < 16; ++r) O[dc][r] *= alpha;

      // ---- O^T += V^T P^T : B-frag for k-step s = sv regs [8(s&1)..+7] ----
#pragma unroll
      for (int s = 0; s < 4; ++s) {
        const int c = s >> 1, o = (s & 1) * 4;
        U8 b;
        b.u[0] = pk[c][o]; b.u[1] = pk[c][o + 1];
        b.u[2] = pk[c][o + 2]; b.u[3] = pk[c][o + 3];
        const int blk = ((2 * s + half) ^ l7) << 3;
#pragma unroll
        for (int dc = 0; dc < 4; ++dc) {
          U8 a; a.us = *(const ushort8*)(lds + 8192 + (dc * 32 + l32) * BN + blk);
          O[dc] = __builtin_amdgcn_mfma_f32_32x32x16_bf16(a.bf, b.bf, O[dc], 0, 0, 0);
        }
      }
    }
    __syncthreads();
  }

  // ---- epilogue: fold halves of l, normalize, store ----
  l += __shfl_xor(l, 32);
  const float linv = 1.0f / l;
  float* orow = ob + (size_t)iq * DH;
#pragma unroll
  for (int dc = 0; dc < 4; ++dc) {
#pragma unroll
    for (int g = 0; g < 4; ++g) {
      float4v o4;
      o4[0] = O[dc][g * 4 + 0] * linv; o4[1] = O[dc][g * 4 + 1] * linv;
      o4[2] = O[dc][g * 4 + 2] * linv; o4[3] = O[dc][g * 4 + 3] * linv;
      *(float4v*)(orow + dc * 32 + g * 8 + half * 4) = o4;
    }
  }
}

extern "C" void kernel_launch(void* const* d_in, const int* in_sizes, int n_in,
                              void* d_out, int out_size, void* d_ws, size_t ws_size,
                              hipStream_t stream) {
  const float* q = (const float*)d_in[0];
  const float* k = (const float*)d_in[1];
  const float* v = (const float*)d_in[2];
  float* o = (float*)d_out;
  const int bh_count = in_sizes[0] / (T_SEQ * DH);   // 64
  ushort_t* ws = (ushort_t*)d_ws;                    // 64 MB used

  pack_kv<<<dim3(bh_count * NT), 256, 0, stream>>>(k, v, ws);
  swa_fwd<<<dim3(T_SEQ / BM, bh_count), 256, 0, stream>>>(q, ws, o);
}